// Round 5
// baseline (1144.513 us; speedup 1.0000x reference)
//
#include <hip/hip_runtime.h>
#include <hip/hip_bf16.h>

// Problem constants
#define SZ    2048
#define SLEN  128
#define DWE   100
#define DPE   5
#define DEE   100
#define DC    300
#define CIN   210
#define KLOC  10
#define OUTW  1500
#define DR    34

// GEMM layout: only word(100)+pos1(5)+pos2(5)=110 channels go through MFMA.
#define KP    128    // padded K
#define LCOLS 136    // XT row stride in bf16 elems (272 B -> 2-way bank spread, free)
#define LROWS 130    // 128 tokens + 2 zero pad rows
#define CPAD  320    // padded out-channels

typedef short short8 __attribute__((ext_vector_type(8)));
typedef float f32x4 __attribute__((ext_vector_type(4)));

static __device__ __forceinline__ unsigned short f2b(float f) {
  return __builtin_bit_cast(unsigned short, __float2bfloat16(f));
}

// wk[kk][c][i] bf16 [3][320][128]; real for c<300, i<110, else 0
__global__ void prep_wk(const float* __restrict__ conv_w, unsigned short* __restrict__ wk) {
  int idx = blockIdx.x * 256 + threadIdx.x;
  if (idx >= 3 * CPAD * KP) return;
  int i  = idx & (KP - 1);
  int c  = (idx / KP) % CPAD;
  int kk = idx / (KP * CPAD);
  float v = 0.f;
  if (c < DC && i < 110) v = conv_w[(c * CIN + i) * 3 + kk];
  wk[idx] = f2b(v);
}

// evconv[st][kk][c] fp32: event-channel conv contribution per tap (+bias folded into kk==1)
__global__ void prep_ev(const float* __restrict__ conv_w, const float* __restrict__ event_emb,
                        const float* __restrict__ conv_b, float* __restrict__ evconv) {
  int idx = blockIdx.x * 256 + threadIdx.x;
  if (idx >= DR * 3 * DC) return;
  int c  = idx % DC;
  int kk = (idx / DC) % 3;
  int st = idx / (3 * DC);
  float v = 0.f;
  if (st != 0) {  // padding_idx=0 on event_emb
    const float* wrow = conv_w + (c * CIN + 110) * 3 + kk;  // stride 3 over i
    const float* e = event_emb + st * DEE;
    for (int i = 0; i < DEE; ++i) v += wrow[3 * i] * e[i];
  }
  if (kk == 1) v += conv_b[c];
  evconv[idx] = v;
}

__global__ __launch_bounds__(512, 8) void dmcnn_main(
    const int* __restrict__ inp, const int* __restrict__ pos1, const int* __restrict__ pos2,
    const int* __restrict__ loc, const int* __restrict__ loc_mark, const int* __restrict__ subtype,
    const float* __restrict__ maskL, const float* __restrict__ maskM, const float* __restrict__ maskR,
    const float* __restrict__ word_emb, const float* __restrict__ pos_emb,
    const unsigned short* __restrict__ wk, const float* __restrict__ evconv,
    float* __restrict__ out)
{
  __shared__ unsigned short XT[LROWS * LCOLS];  // 35360 B; XT[t+1][i]; reused as pool later
  __shared__ int cw[4];                         // per-wave popcounts of maskL/maskM

  const int s   = blockIdx.x;
  const int tid = threadIdx.x;

  // ---- phase 0 (disjoint writes, single barrier after) ----
  // zero pad rows 0 and 129 (cols 0..127)
  if (tid < 64)        ((unsigned*)XT)[tid] = 0u;
  else if (tid < 128)  ((unsigned*)(XT + 129 * LCOLS))[tid - 64] = 0u;

  // recover cut points a,b from the masks via ballot (t = tid for waves 0,1)
  if (tid < 128) {
    const int inL = maskL[s * SLEN + tid] > 0.5f;
    const int inM = maskM[s * SLEN + tid] > 0.5f;
    unsigned long long bL = __ballot(inL);
    unsigned long long bM = __ballot(inM);
    if ((tid & 63) == 0) {
      cw[tid >> 6]       = __popcll(bL);
      cw[2 + (tid >> 6)] = __popcll(bM);
    }
  }

  // stage XT: 4 threads per token
  {
    const int t = tid >> 2, q = tid & 3;
    unsigned short* row = &XT[(t + 1) * LCOLS];
    if (q < 2) {  // word halves
      const int w = inp[s * SLEN + t];
      const float* wp = word_emb + (size_t)w * DWE + q * 50;
      #pragma unroll
      for (int j = 0; j < 25; ++j) {
        unsigned u = 0u;
        if (w != 0) {  // padding_idx=0
          float2 v = ((const float2*)wp)[j];
          u = (unsigned)f2b(v.x) | ((unsigned)f2b(v.y) << 16);
        }
        *(unsigned*)&row[q * 50 + j * 2] = u;
      }
    } else {  // positions + K-pad cols
      const int p = (q == 2 ? pos1 : pos2)[s * SLEN + t];
      const float* pp = pos_emb + p * DPE;
      #pragma unroll
      for (int d = 0; d < DPE; ++d) row[DWE + (q - 2) * DPE + d] = f2b(pp[d]);
      #pragma unroll
      for (int d = 0; d < 9; ++d) row[110 + 9 * (q - 2) + d] = 0;
    }
  }
  __syncthreads();

  // ---- GEMM: wave (wc,wt): channels [80wc,80wc+80) x tokens [64wt,64wt+64) ----
  const int wv   = tid >> 6;
  const int wc   = wv & 3, wt = wv >> 2;
  const int lane = tid & 63;
  const int r16  = lane & 15, q16 = lane >> 4;

  f32x4 acc[4][5];
  #pragma unroll
  for (int tt = 0; tt < 4; ++tt)
    #pragma unroll
    for (int ci = 0; ci < 5; ++ci) acc[tt][ci] = (f32x4){0.f, 0.f, 0.f, 0.f};

  const unsigned short* wbase = wk + (size_t)(80 * wc + r16) * KP + q16 * 8;
  #pragma unroll 1
  for (int ks = 0; ks < 12; ++ks) {
    const int kk = ks >> 2, kt = ks & 3;
    short8 wf[5];
    #pragma unroll
    for (int ci = 0; ci < 5; ++ci)
      wf[ci] = *(const short8*)(wbase + (size_t)(kk * CPAD + 16 * ci) * KP + kt * 32);
    #pragma unroll
    for (int tt = 0; tt < 4; ++tt) {
      short8 xf = *(const short8*)&XT[(64 * wt + 16 * tt + r16 + kk) * LCOLS + kt * 32 + q16 * 8];
      #pragma unroll
      for (int ci = 0; ci < 5; ++ci)
        acc[tt][ci] = __builtin_amdgcn_mfma_f32_16x16x32_bf16(xf, wf[ci], acc[tt][ci], 0, 0, 0);
    }
  }

  // ---- per-wave partial pooled max; D[row=t][col=c], t=64wt+16tt+4q16+j, c=80wc+16ci+r16 ----
  const int acut = cw[0] + cw[1];
  const int bcut = acut + cw[2] + cw[3];
  const int st   = subtype[s];
  const float* evc = evconv + (size_t)st * 3 * DC;
  float* orow = out + (size_t)s * OUTW;

  float pL[5], pM[5], pR[5];
  #pragma unroll
  for (int ci = 0; ci < 5; ++ci) {
    const int c = 80 * wc + 16 * ci + r16;
    const float s0 = evc[c < DC ? c : 0], s1 = evc[(c < DC ? c : 0) + DC], s2 = evc[(c < DC ? c : 0) + 2 * DC];
    const float base = s0 + s1 + s2;   // bias folded into s1
    float rL = 0.f, rM = 0.f, rR = 0.f;  // masked-out positions contribute exactly 0
    #pragma unroll
    for (int tt = 0; tt < 4; ++tt) {
      #pragma unroll
      for (int j = 0; j < 4; ++j) {
        const int t = 64 * wt + 16 * tt + 4 * q16 + j;
        float v = acc[tt][ci][j] + base;
        if (t == 0)   v -= s0;   // top boundary: tap kk=0 reads pad
        if (t == 127) v -= s2;   // bottom boundary: tap kk=2 reads pad
        if (t < acut)      rL = fmaxf(rL, v);
        else if (t < bcut) rM = fmaxf(rM, v);
        else               rR = fmaxf(rR, v);
      }
    }
    #pragma unroll
    for (int off = 16; off < 64; off <<= 1) {
      rL = fmaxf(rL, __shfl_xor(rL, off));
      rM = fmaxf(rM, __shfl_xor(rM, off));
      rR = fmaxf(rR, __shfl_xor(rR, off));
    }
    pL[ci] = rL; pM[ci] = rM; pR[ci] = rR;
  }

  // ---- cross-t-half combine via LDS pool aliased onto dead XT ----
  __syncthreads();                      // all waves done reading XT
  float* pool = (float*)XT;             // pool[(wt*320 + c)*4 + {0,1,2}], 10240 B
  if (q16 == 0) {
    #pragma unroll
    for (int ci = 0; ci < 5; ++ci) {
      const int c = 80 * wc + 16 * ci + r16;
      float* p = pool + ((size_t)wt * CPAD + c) * 4;
      p[0] = pL[ci]; p[1] = pM[ci]; p[2] = pR[ci];
    }
  }
  __syncthreads();
  if (tid < DC) {
    const float* p0 = pool + (size_t)tid * 4;
    const float* p1 = pool + (size_t)(CPAD + tid) * 4;
    orow[tid]          = tanhf(fmaxf(p0[0], p1[0]));
    orow[DC + tid]     = tanhf(fmaxf(p0[1], p1[1]));
    orow[2 * DC + tid] = tanhf(fmaxf(p0[2], p1[2]));
  }

  // ---- loc_embeds: out[s][900..1499], exact fp32 ----
  const int mark = loc_mark[s];
  for (int j = tid; j < 600; j += 512) {
    float v;
    if (j < 400) {
      const int k = j / 100, d = j % 100;
      const int idx = loc[s * KLOC + k];
      v = (idx == 0) ? 0.f : word_emb[(size_t)idx * DWE + d];
    } else if (j < 500) {
      const int d = j - 400;
      float sum = 0.f;
      for (int k = 4; k < 4 + mark; ++k) {
        const int idx = loc[s * KLOC + k];
        sum += (idx == 0) ? 0.f : word_emb[(size_t)idx * DWE + d];
      }
      v = sum / (float)mark;
    } else {
      const int d = j - 500;
      const int idx = loc[s * KLOC + 4 + mark];
      v = (idx == 0) ? 0.f : word_emb[(size_t)idx * DWE + d];
    }
    orow[900 + j] = tanhf(v);
  }
}

extern "C" void kernel_launch(void* const* d_in, const int* in_sizes, int n_in,
                              void* d_out, int out_size, void* d_ws, size_t ws_size,
                              hipStream_t stream) {
  const int*   inp       = (const int*)d_in[0];
  const int*   pos1      = (const int*)d_in[1];
  const int*   pos2      = (const int*)d_in[2];
  const int*   loc       = (const int*)d_in[3];
  const int*   loc_mark  = (const int*)d_in[4];
  const int*   subtype   = (const int*)d_in[5];
  const float* maskL     = (const float*)d_in[6];
  const float* maskM     = (const float*)d_in[7];
  const float* maskR     = (const float*)d_in[8];
  const float* word_emb  = (const float*)d_in[9];
  const float* pos_emb   = (const float*)d_in[10];
  const float* event_emb = (const float*)d_in[11];
  const float* conv_w    = (const float*)d_in[12];
  const float* conv_b    = (const float*)d_in[13];

  unsigned short* wk = (unsigned short*)d_ws;                    // 3*320*128*2 = 245760 B
  float* evconv = (float*)((char*)d_ws + 3 * CPAD * KP * 2);     // 34*3*300*4 = 122400 B
  float* out = (float*)d_out;

  prep_wk<<<(3 * CPAD * KP + 255) / 256, 256, 0, stream>>>(conv_w, wk);
  prep_ev<<<(DR * 3 * DC + 255) / 256, 256, 0, stream>>>(conv_w, event_emb, conv_b, evconv);
  dmcnn_main<<<SZ, 512, 0, stream>>>(inp, pos1, pos2, loc, loc_mark, subtype,
      maskL, maskM, maskR, word_emb, pos_emb, wk, evconv, out);
}

// Round 6
// 268.907 us; speedup vs baseline: 4.2562x; 4.2562x over previous
//
#include <hip/hip_runtime.h>
#include <hip/hip_bf16.h>

// Problem constants
#define SZ    2048
#define SLEN  128
#define DWE   100
#define DPE   5
#define DEE   100
#define DC    300
#define CIN   210
#define KLOC  10
#define OUTW  1500
#define DR    34

// GEMM layout: only word(100)+pos1(5)+pos2(5)=110 channels go through MFMA.
#define KP    128    // padded K
#define LCOLS 136    // XT row stride in bf16 elems (272 B -> 2-way bank spread, free)
#define LROWS 130    // 128 tokens + 2 zero pad rows
#define CPAD  320    // padded out-channels

typedef short short8 __attribute__((ext_vector_type(8)));
typedef float f32x4 __attribute__((ext_vector_type(4)));

static __device__ __forceinline__ unsigned short f2b(float f) {
  return __builtin_bit_cast(unsigned short, __float2bfloat16(f));
}

// wk[kk][c][i] bf16 [3][320][128]; real for c<300, i<110, else 0
__global__ void prep_wk(const float* __restrict__ conv_w, unsigned short* __restrict__ wk) {
  int idx = blockIdx.x * 256 + threadIdx.x;
  if (idx >= 3 * CPAD * KP) return;
  int i  = idx & (KP - 1);
  int c  = (idx / KP) % CPAD;
  int kk = idx / (KP * CPAD);
  float v = 0.f;
  if (c < DC && i < 110) v = conv_w[(c * CIN + i) * 3 + kk];
  wk[idx] = f2b(v);
}

// evconv[st][kk][c] fp32: event-channel conv contribution per tap (+bias folded into kk==1)
__global__ void prep_ev(const float* __restrict__ conv_w, const float* __restrict__ event_emb,
                        const float* __restrict__ conv_b, float* __restrict__ evconv) {
  int idx = blockIdx.x * 256 + threadIdx.x;
  if (idx >= DR * 3 * DC) return;
  int c  = idx % DC;
  int kk = (idx / DC) % 3;
  int st = idx / (3 * DC);
  float v = 0.f;
  if (st != 0) {  // padding_idx=0 on event_emb
    const float* wrow = conv_w + (c * CIN + 110) * 3 + kk;  // stride 3 over i
    const float* e = event_emb + st * DEE;
    for (int i = 0; i < DEE; ++i) v += wrow[3 * i] * e[i];
  }
  if (kk == 1) v += conv_b[c];
  evconv[idx] = v;
}

// launch_bounds(512,4): 4 waves/EU = 16 waves/CU = 2 blocks/CU -> 128-reg/thread budget.
// (512,8) forced a 64-reg budget < the 80-reg accumulator tile -> total spill (round 5).
__global__ __launch_bounds__(512, 4) void dmcnn_main(
    const int* __restrict__ inp, const int* __restrict__ pos1, const int* __restrict__ pos2,
    const int* __restrict__ loc, const int* __restrict__ loc_mark, const int* __restrict__ subtype,
    const float* __restrict__ maskL, const float* __restrict__ maskM, const float* __restrict__ maskR,
    const float* __restrict__ word_emb, const float* __restrict__ pos_emb,
    const unsigned short* __restrict__ wk, const float* __restrict__ evconv,
    float* __restrict__ out)
{
  __shared__ unsigned short XT[LROWS * LCOLS];  // 35360 B; XT[t+1][i]
  __shared__ float pool[2 * CPAD * 4];          // 10240 B; [wt][c][{L,M,R,pad}]
  __shared__ int cw[4];                         // per-wave popcounts of maskL/maskM

  const int s   = blockIdx.x;
  const int tid = threadIdx.x;

  // ---- phase 0 (disjoint writes, single barrier after) ----
  // zero pad rows 0 and 129 (cols 0..127)
  if (tid < 64)        ((unsigned*)XT)[tid] = 0u;
  else if (tid < 128)  ((unsigned*)(XT + 129 * LCOLS))[tid - 64] = 0u;

  // recover cut points a,b from the masks via ballot (t = tid for waves 0,1)
  if (tid < 128) {
    const int inL = maskL[s * SLEN + tid] > 0.5f;
    const int inM = maskM[s * SLEN + tid] > 0.5f;
    unsigned long long bL = __ballot(inL);
    unsigned long long bM = __ballot(inM);
    if ((tid & 63) == 0) {
      cw[tid >> 6]       = __popcll(bL);
      cw[2 + (tid >> 6)] = __popcll(bM);
    }
  }

  // stage XT: 4 threads per token
  {
    const int t = tid >> 2, q = tid & 3;
    unsigned short* row = &XT[(t + 1) * LCOLS];
    if (q < 2) {  // word halves
      const int w = inp[s * SLEN + t];
      const float* wp = word_emb + (size_t)w * DWE + q * 50;
      #pragma unroll
      for (int j = 0; j < 25; ++j) {
        unsigned u = 0u;
        if (w != 0) {  // padding_idx=0
          float2 v = ((const float2*)wp)[j];
          u = (unsigned)f2b(v.x) | ((unsigned)f2b(v.y) << 16);
        }
        *(unsigned*)&row[q * 50 + j * 2] = u;
      }
    } else {  // positions + K-pad cols
      const int p = (q == 2 ? pos1 : pos2)[s * SLEN + t];
      const float* pp = pos_emb + p * DPE;
      #pragma unroll
      for (int d = 0; d < DPE; ++d) row[DWE + (q - 2) * DPE + d] = f2b(pp[d]);
      #pragma unroll
      for (int d = 0; d < 9; ++d) row[110 + 9 * (q - 2) + d] = 0;
    }
  }
  __syncthreads();

  // ---- GEMM: wave (wc,wt): channels [80wc,80wc+80) x tokens [64wt,64wt+64) ----
  const int wv   = tid >> 6;
  const int wc   = wv & 3, wt = wv >> 2;
  const int lane = tid & 63;
  const int r16  = lane & 15, q16 = lane >> 4;

  f32x4 acc[4][5];
  #pragma unroll
  for (int tt = 0; tt < 4; ++tt)
    #pragma unroll
    for (int ci = 0; ci < 5; ++ci) acc[tt][ci] = (f32x4){0.f, 0.f, 0.f, 0.f};

  const unsigned short* wbase = wk + (size_t)(80 * wc + r16) * KP + q16 * 8;
  #pragma unroll 1
  for (int ks = 0; ks < 12; ++ks) {
    const int kk = ks >> 2, kt = ks & 3;
    short8 wf[5];
    #pragma unroll
    for (int ci = 0; ci < 5; ++ci)
      wf[ci] = *(const short8*)(wbase + (size_t)(kk * CPAD + 16 * ci) * KP + kt * 32);
    #pragma unroll
    for (int tt = 0; tt < 4; ++tt) {
      short8 xf = *(const short8*)&XT[(64 * wt + 16 * tt + r16 + kk) * LCOLS + kt * 32 + q16 * 8];
      #pragma unroll
      for (int ci = 0; ci < 5; ++ci)
        acc[tt][ci] = __builtin_amdgcn_mfma_f32_16x16x32_bf16(xf, wf[ci], acc[tt][ci], 0, 0, 0);
    }
  }

  // ---- per-wave pooled max; D[row=t][col=c], t=64wt+16tt+4q16+j, c=80wc+16ci+r16 ----
  const int acut = cw[0] + cw[1];
  const int bcut = acut + cw[2] + cw[3];
  const int st   = subtype[s];
  const float* evc = evconv + (size_t)st * 3 * DC;
  float* orow = out + (size_t)s * OUTW;

  #pragma unroll
  for (int ci = 0; ci < 5; ++ci) {
    const int c = 80 * wc + 16 * ci + r16;
    const int cc = c < DC ? c : 0;
    const float s0 = evc[cc], s1 = evc[cc + DC], s2 = evc[cc + 2 * DC];
    const float base = s0 + s1 + s2;   // bias folded into s1
    float rL = 0.f, rM = 0.f, rR = 0.f;  // masked-out positions contribute exactly 0
    #pragma unroll
    for (int tt = 0; tt < 4; ++tt) {
      #pragma unroll
      for (int j = 0; j < 4; ++j) {
        const int t = 64 * wt + 16 * tt + 4 * q16 + j;
        float v = acc[tt][ci][j] + base;
        if (t == 0)   v -= s0;   // top boundary: tap kk=0 reads pad
        if (t == 127) v -= s2;   // bottom boundary: tap kk=2 reads pad
        if (t < acut)      rL = fmaxf(rL, v);
        else if (t < bcut) rM = fmaxf(rM, v);
        else               rR = fmaxf(rR, v);
      }
    }
    #pragma unroll
    for (int off = 16; off < 64; off <<= 1) {
      rL = fmaxf(rL, __shfl_xor(rL, off));
      rM = fmaxf(rM, __shfl_xor(rM, off));
      rR = fmaxf(rR, __shfl_xor(rR, off));
    }
    if (q16 == 0) {  // separate pool buffer: no barrier needed before write
      float* p = pool + ((size_t)wt * CPAD + c) * 4;
      p[0] = rL; p[1] = rM; p[2] = rR;
    }
  }

  __syncthreads();
  if (tid < DC) {
    const float* p0 = pool + (size_t)tid * 4;
    const float* p1 = pool + (size_t)(CPAD + tid) * 4;
    orow[tid]          = tanhf(fmaxf(p0[0], p1[0]));
    orow[DC + tid]     = tanhf(fmaxf(p0[1], p1[1]));
    orow[2 * DC + tid] = tanhf(fmaxf(p0[2], p1[2]));
  }

  // ---- loc_embeds: out[s][900..1499], exact fp32 ----
  const int mark = loc_mark[s];
  for (int j = tid; j < 600; j += 512) {
    float v;
    if (j < 400) {
      const int k = j / 100, d = j % 100;
      const int idx = loc[s * KLOC + k];
      v = (idx == 0) ? 0.f : word_emb[(size_t)idx * DWE + d];
    } else if (j < 500) {
      const int d = j - 400;
      float sum = 0.f;
      for (int k = 4; k < 4 + mark; ++k) {
        const int idx = loc[s * KLOC + k];
        sum += (idx == 0) ? 0.f : word_emb[(size_t)idx * DWE + d];
      }
      v = sum / (float)mark;
    } else {
      const int d = j - 500;
      const int idx = loc[s * KLOC + 4 + mark];
      v = (idx == 0) ? 0.f : word_emb[(size_t)idx * DWE + d];
    }
    orow[900 + j] = tanhf(v);
  }
}

extern "C" void kernel_launch(void* const* d_in, const int* in_sizes, int n_in,
                              void* d_out, int out_size, void* d_ws, size_t ws_size,
                              hipStream_t stream) {
  const int*   inp       = (const int*)d_in[0];
  const int*   pos1      = (const int*)d_in[1];
  const int*   pos2      = (const int*)d_in[2];
  const int*   loc       = (const int*)d_in[3];
  const int*   loc_mark  = (const int*)d_in[4];
  const int*   subtype   = (const int*)d_in[5];
  const float* maskL     = (const float*)d_in[6];
  const float* maskM     = (const float*)d_in[7];
  const float* maskR     = (const float*)d_in[8];
  const float* word_emb  = (const float*)d_in[9];
  const float* pos_emb   = (const float*)d_in[10];
  const float* event_emb = (const float*)d_in[11];
  const float* conv_w    = (const float*)d_in[12];
  const float* conv_b    = (const float*)d_in[13];

  unsigned short* wk = (unsigned short*)d_ws;                    // 3*320*128*2 = 245760 B
  float* evconv = (float*)((char*)d_ws + 3 * CPAD * KP * 2);     // 34*3*300*4 = 122400 B
  float* out = (float*)d_out;

  prep_wk<<<(3 * CPAD * KP + 255) / 256, 256, 0, stream>>>(conv_w, wk);
  prep_ev<<<(DR * 3 * DC + 255) / 256, 256, 0, stream>>>(conv_w, event_emb, conv_b, evconv);
  dmcnn_main<<<SZ, 512, 0, stream>>>(inp, pos1, pos2, loc, loc_mark, subtype,
      maskL, maskM, maskR, word_emb, pos_emb, wk, evconv, out);
}

// Round 7
// 248.215 us; speedup vs baseline: 4.6110x; 1.0834x over previous
//
#include <hip/hip_runtime.h>
#include <hip/hip_bf16.h>

// Problem constants
#define SZ    2048
#define SLEN  128
#define DWE   100
#define DPE   5
#define DEE   100
#define DC    300
#define CIN   210
#define KLOC  10
#define OUTW  1500
#define DR    34

// GEMM layout: only word(100)+pos1(5)+pos2(5)=110 channels go through MFMA.
#define KP    128    // padded K
#define LCOLS 136    // XT row stride in bf16 elems (272 B)
#define LROWS 130    // 128 tokens + 2 zero pad rows
#define CPAD  320    // padded out-channels

typedef short short8 __attribute__((ext_vector_type(8)));
typedef float f32x4 __attribute__((ext_vector_type(4)));

static __device__ __forceinline__ unsigned short f2b(float f) {
  return __builtin_bit_cast(unsigned short, __float2bfloat16(f));
}

// packed f32x2 -> bf16x2 (RNE), single instruction on gfx950
static __device__ __forceinline__ unsigned cvt_pk_bf16(float lo, float hi) {
  unsigned r;
  asm volatile("v_cvt_pk_bf16_f32 %0, %1, %2" : "=v"(r) : "v"(lo), "v"(hi));
  return r;
}

// fast tanh: (e^2x - 1) / (e^2x + 1); ~8 instrs vs ~35 for libm tanhf
static __device__ __forceinline__ float ftanh(float x) {
  x = fminf(fmaxf(x, -15.f), 15.f);
  float e = __expf(2.0f * x);
  return (e - 1.0f) * __builtin_amdgcn_rcpf(e + 1.0f);
}

// wk[kk][c][i] bf16 [3][320][128]; real for c<300, i<110, else 0
__global__ void prep_wk(const float* __restrict__ conv_w, unsigned short* __restrict__ wk) {
  int idx = blockIdx.x * 256 + threadIdx.x;
  if (idx >= 3 * CPAD * KP) return;
  int i  = idx & (KP - 1);
  int c  = (idx / KP) % CPAD;
  int kk = idx / (KP * CPAD);
  float v = 0.f;
  if (c < DC && i < 110) v = conv_w[(c * CIN + i) * 3 + kk];
  wk[idx] = f2b(v);
}

// evconv[st][kk][c] fp32: event-channel conv per tap (+bias folded into kk==1).
// 4 threads per output (i-split 25 each) + quad shuffle reduce: round-6's version
// was a 120-block serial-uncoalesced latency disaster (~80 us).
__global__ void prep_ev(const float* __restrict__ conv_w, const float* __restrict__ event_emb,
                        const float* __restrict__ conv_b, float* __restrict__ evconv) {
  int gid = blockIdx.x * 256 + threadIdx.x;
  int o = gid >> 2, sub = gid & 3;
  if (o >= DR * 3 * DC) return;   // whole quads exit together (122400 % 4 == 0)
  int c  = o % DC;
  int kk = (o / DC) % 3;
  int st = o / (3 * DC);
  float v = 0.f;
  if (st != 0) {  // padding_idx=0 on event_emb
    const float* wrow = conv_w + (c * CIN + 110) * 3 + kk;
    const float* e = event_emb + st * DEE;
    #pragma unroll
    for (int i = 0; i < 25; ++i) v += wrow[3 * (sub * 25 + i)] * e[sub * 25 + i];
  }
  v += __shfl_xor(v, 1);
  v += __shfl_xor(v, 2);
  if (sub == 0) evconv[o] = v + (kk == 1 ? conv_b[c] : 0.f);
}

// launch_bounds(512,4): 4 waves/EU = 16 waves/CU = 2 blocks/CU -> 128-reg budget.
// (512,8) forced a 64-reg budget < the 80-reg accumulator tile -> total spill (round 5).
__global__ __launch_bounds__(512, 4) void dmcnn_main(
    const int* __restrict__ inp, const int* __restrict__ pos1, const int* __restrict__ pos2,
    const int* __restrict__ loc, const int* __restrict__ loc_mark, const int* __restrict__ subtype,
    const float* __restrict__ maskL, const float* __restrict__ maskM, const float* __restrict__ maskR,
    const float* __restrict__ word_emb, const float* __restrict__ pos_emb,
    const unsigned short* __restrict__ wk, const float* __restrict__ evconv,
    float* __restrict__ out)
{
  __shared__ unsigned short XT[LROWS * LCOLS];  // 35360 B; XT[t+1][i]
  __shared__ float pool[2 * CPAD * 4];          // 10240 B; [wt][c][{L,M,R,pad}]
  __shared__ int cw[4];

  const int s   = blockIdx.x;
  const int tid = threadIdx.x;

  // ---- phase 0 (disjoint writes, single barrier after) ----
  if (tid < 64)        ((unsigned*)XT)[tid] = 0u;                          // pad row 0
  else if (tid < 128)  ((unsigned*)(XT + 129 * LCOLS))[tid - 64] = 0u;     // pad row 129

  // recover cut points a,b from masks via ballot (t = tid for waves 0,1)
  if (tid < 128) {
    const int inL = maskL[s * SLEN + tid] > 0.5f;
    const int inM = maskM[s * SLEN + tid] > 0.5f;
    unsigned long long bL = __ballot(inL);
    unsigned long long bM = __ballot(inM);
    if ((tid & 63) == 0) {
      cw[tid >> 6]       = __popcll(bL);
      cw[2 + (tid >> 6)] = __popcll(bM);
    }
  }

  // stage XT: 4 threads per token; word row via float4 + packed bf16 cvt
  {
    const int t = tid >> 2, q = tid & 3;
    unsigned short* row = &XT[(t + 1) * LCOLS];
    const int w = inp[s * SLEN + t];
    const float4* wp = (const float4*)(word_emb + (size_t)w * DWE);  // rows are 400 B, 16B-aligned
    for (int j = q; j < 25; j += 4) {   // 7/6/6/6 float4's per thread
      float4 v = wp[j];
      unsigned lo = cvt_pk_bf16(v.x, v.y);
      unsigned hi = cvt_pk_bf16(v.z, v.w);
      if (w == 0) { lo = 0u; hi = 0u; }   // padding_idx=0
      *(uint2*)&row[4 * j] = make_uint2(lo, hi);   // 8B store, aligned (272*(t+1)+8j)
    }
    if (q == 1 || q == 2) {  // positions (5 floats, unaligned rows -> scalar)
      const int p = (q == 1 ? pos1 : pos2)[s * SLEN + t];
      const float* pp = pos_emb + p * DPE;
      #pragma unroll
      for (int d = 0; d < DPE; ++d) row[DWE + (q - 1) * DPE + d] = f2b(pp[d]);
    } else if (q == 3) {     // K-pad cols 110..127
      #pragma unroll
      for (int d = 0; d < 9; ++d) *(unsigned*)&row[110 + 2 * d] = 0u;
    }
  }
  __syncthreads();

  // ---- GEMM: wave (wc,wt): channels [80wc,80wc+80) x tokens [64wt,64wt+64) ----
  const int wv   = tid >> 6;
  const int wc   = wv & 3, wt = wv >> 2;
  const int lane = tid & 63;
  const int r16  = lane & 15, q16 = lane >> 4;

  f32x4 acc[4][5];
  #pragma unroll
  for (int tt = 0; tt < 4; ++tt)
    #pragma unroll
    for (int ci = 0; ci < 5; ++ci) acc[tt][ci] = (f32x4){0.f, 0.f, 0.f, 0.f};

  const unsigned short* wbase = wk + (size_t)(80 * wc + r16) * KP + q16 * 8;
  #pragma unroll 1
  for (int ks = 0; ks < 12; ++ks) {
    const int kk = ks >> 2, kt = ks & 3;
    short8 wf[5];
    #pragma unroll
    for (int ci = 0; ci < 5; ++ci)
      wf[ci] = *(const short8*)(wbase + (size_t)(kk * CPAD + 16 * ci) * KP + kt * 32);
    #pragma unroll
    for (int tt = 0; tt < 4; ++tt) {
      short8 xf = *(const short8*)&XT[(64 * wt + 16 * tt + r16 + kk) * LCOLS + kt * 32 + q16 * 8];
      #pragma unroll
      for (int ci = 0; ci < 5; ++ci)
        acc[tt][ci] = __builtin_amdgcn_mfma_f32_16x16x32_bf16(xf, wf[ci], acc[tt][ci], 0, 0, 0);
    }
  }

  // ---- per-wave pooled max; D[row=t][col=c], t=64wt+16tt+4q16+j, c=80wc+16ci+r16 ----
  const int acut = cw[0] + cw[1];
  const int bcut = acut + cw[2] + cw[3];
  const int st   = subtype[s];
  const float* evc = evconv + (size_t)st * 3 * DC;
  float* orow = out + (size_t)s * OUTW;

  #pragma unroll
  for (int ci = 0; ci < 5; ++ci) {
    const int c = 80 * wc + 16 * ci + r16;
    const int cc = c < DC ? c : 0;
    const float s0 = evc[cc], s1 = evc[cc + DC], s2 = evc[cc + 2 * DC];
    const float base = s0 + s1 + s2;   // bias folded into s1
    float rL = 0.f, rM = 0.f, rR = 0.f;  // masked-out positions contribute exactly 0
    #pragma unroll
    for (int tt = 0; tt < 4; ++tt) {
      #pragma unroll
      for (int j = 0; j < 4; ++j) {
        const int t = 64 * wt + 16 * tt + 4 * q16 + j;
        float v = acc[tt][ci][j] + base;
        if (t == 0)   v -= s0;
        if (t == 127) v -= s2;
        if (t < acut)      rL = fmaxf(rL, v);
        else if (t < bcut) rM = fmaxf(rM, v);
        else               rR = fmaxf(rR, v);
      }
    }
    #pragma unroll
    for (int off = 16; off < 64; off <<= 1) {
      rL = fmaxf(rL, __shfl_xor(rL, off));
      rM = fmaxf(rM, __shfl_xor(rM, off));
      rR = fmaxf(rR, __shfl_xor(rR, off));
    }
    if (q16 == 0) {
      float* p = pool + ((size_t)wt * CPAD + c) * 4;
      p[0] = rL; p[1] = rM; p[2] = rR;
    }
  }

  __syncthreads();
  if (tid < DC) {
    const float* p0 = pool + (size_t)tid * 4;
    const float* p1 = pool + (size_t)(CPAD + tid) * 4;
    orow[tid]          = ftanh(fmaxf(p0[0], p1[0]));
    orow[DC + tid]     = ftanh(fmaxf(p0[1], p1[1]));
    orow[2 * DC + tid] = ftanh(fmaxf(p0[2], p1[2]));
  }

  // ---- loc_embeds: out[s][900..1499], exact fp32 gathers ----
  const int mark = loc_mark[s];
  for (int j = tid; j < 600; j += 512) {
    float v;
    if (j < 400) {
      const int k = j / 100, d = j % 100;
      const int idx = loc[s * KLOC + k];
      v = (idx == 0) ? 0.f : word_emb[(size_t)idx * DWE + d];
    } else if (j < 500) {
      const int d = j - 400;
      float sum = 0.f;
      for (int k = 4; k < 4 + mark; ++k) {
        const int idx = loc[s * KLOC + k];
        sum += (idx == 0) ? 0.f : word_emb[(size_t)idx * DWE + d];
      }
      v = sum / (float)mark;
    } else {
      const int d = j - 500;
      const int idx = loc[s * KLOC + 4 + mark];
      v = (idx == 0) ? 0.f : word_emb[(size_t)idx * DWE + d];
    }
    orow[900 + j] = ftanh(v);
  }
}

extern "C" void kernel_launch(void* const* d_in, const int* in_sizes, int n_in,
                              void* d_out, int out_size, void* d_ws, size_t ws_size,
                              hipStream_t stream) {
  const int*   inp       = (const int*)d_in[0];
  const int*   pos1      = (const int*)d_in[1];
  const int*   pos2      = (const int*)d_in[2];
  const int*   loc       = (const int*)d_in[3];
  const int*   loc_mark  = (const int*)d_in[4];
  const int*   subtype   = (const int*)d_in[5];
  const float* maskL     = (const float*)d_in[6];
  const float* maskM     = (const float*)d_in[7];
  const float* maskR     = (const float*)d_in[8];
  const float* word_emb  = (const float*)d_in[9];
  const float* pos_emb   = (const float*)d_in[10];
  const float* event_emb = (const float*)d_in[11];
  const float* conv_w    = (const float*)d_in[12];
  const float* conv_b    = (const float*)d_in[13];

  unsigned short* wk = (unsigned short*)d_ws;                    // 3*320*128*2 = 245760 B
  float* evconv = (float*)((char*)d_ws + 3 * CPAD * KP * 2);     // 34*3*300*4 = 122400 B
  float* out = (float*)d_out;

  prep_wk<<<(3 * CPAD * KP + 255) / 256, 256, 0, stream>>>(conv_w, wk);
  prep_ev<<<(DR * 3 * DC * 4 + 255) / 256, 256, 0, stream>>>(conv_w, event_emb, conv_b, evconv);
  dmcnn_main<<<SZ, 512, 0, stream>>>(inp, pos1, pos2, loc, loc_mark, subtype,
      maskL, maskM, maskR, word_emb, pos_emb, wk, evconv, out);
}